// Round 9
// baseline (614.145 us; speedup 1.0000x reference)
//
#include <hip/hip_runtime.h>
#include <cstdint>
#include <cstddef>

// ---------------------------------------------------------------------------
// AffineMultiQueryHardAttentionEncoder
//   scores[m] = max_n ( (q[n]*a) . k[m] ), top-64, softmax, sum w_i * V[idx_i]
// R9: persistent gemm, LINEAR keys sweep.
//   - 256 blocks (1/CU), each owns ~4 tiles of 96 keys (2 halves of 48).
//   - A: per half, 192KB contiguous f32 read (fillBuffer-style linear sweep,
//     issued one half AHEAD; vmcnt-paces the compute) -> bf16 LDS [48][1024].
//   - B: qstage (1MB, L2) reg-staged 2 sub-steps ahead, ds_write 1 ahead;
//     per-sub-step barrier is lgkmcnt(0)+s_barrier ONLY (no vmcnt ever).
//   - epilogue per half: max over queries -> scores.
//   - select: hist threshold + exact f32 rescore + final (unchanged, R8).
// ---------------------------------------------------------------------------

typedef __attribute__((ext_vector_type(8))) short bf16x8;
typedef __attribute__((ext_vector_type(4))) float f32x4;

static constexpr int NQ = 512;
static constexpr int DD = 1024;
static constexpr int MK = 100000;
static constexpr int NTILES = 1042;          // ceil(100000 / 96)
static constexpr int CAP = 1024;

// workspace layout (bytes)
static constexpr size_t QSTAGE_OFF   = 0;    // [32 ks][4 g][512 q][16B] = 1 MiB
static constexpr size_t QSTAGE_BYTES = (size_t)32 * 4 * NQ * 16;
static constexpr size_t SCORES_OFF   = QSTAGE_OFF + QSTAGE_BYTES;
static constexpr size_t SCORES_BYTES = (size_t)100032 * 4;
static constexpr size_t CIDX_OFF     = SCORES_OFF + SCORES_BYTES;
static constexpr size_t RESC_OFF     = CIDX_OFF + (size_t)CAP * 4;
static constexpr size_t CNT_OFF      = RESC_OFF + (size_t)CAP * 4;
static constexpr size_t HIST_OFF     = CNT_OFF + 64;
static constexpr size_t VLO_OFF      = HIST_OFF + 8192 * 4;

// gemm LDS: A [48 rows][2048B] = 98304 @0 ; B dbuf 2x32768 @98304 -> 163840
static constexpr int GEMM_LDS = 98304 + 2 * 32768;   // exactly 160 KiB

static __device__ __forceinline__ unsigned short f32_to_bf16_rne(float f) {
    unsigned int u = __float_as_uint(f);
    unsigned int r = (u + 0x7FFFu + ((u >> 16) & 1u)) >> 16;
    return (unsigned short)r;
}
static __device__ __forceinline__ unsigned int xform(float f) {
    unsigned int u = __float_as_uint(f);
    return u ^ ((unsigned int)((int)u >> 31) | 0x80000000u);
}
static __device__ __forceinline__ float unxform(unsigned int u) {
    unsigned int b = (u & 0x80000000u) ? (u ^ 0x80000000u) : ~u;
    return __uint_as_float(b);
}

// ---------------------------------------------------------------------------
// prep_q: qa = q*a -> bf16 RNE, fragment-major:
//   chunk id = (ks*4 + g)*512 + q   holds   qa[q][ks*32 + g*8 .. +7]
// ---------------------------------------------------------------------------
__global__ void prep_q(const float* __restrict__ q, const float* __restrict__ a,
                       unsigned short* __restrict__ qs) {
    int id = blockIdx.x * 256 + threadIdx.x;    // 0..65535
    int qq = id & 511;
    int g  = (id >> 9) & 3;
    int ks = id >> 11;
    int col = ks * 32 + g * 8;

    const float* qrow = q + (size_t)qq * DD + col;
    float4 v0 = *(const float4*)(qrow);
    float4 v1 = *(const float4*)(qrow + 4);
    float4 a0 = *(const float4*)(a + col);
    float4 a1 = *(const float4*)(a + col + 4);
    float f[8] = {v0.x * a0.x, v0.y * a0.y, v0.z * a0.z, v0.w * a0.w,
                  v1.x * a1.x, v1.y * a1.y, v1.z * a1.z, v1.w * a1.w};
    bf16x8 o;
#pragma unroll
    for (int t = 0; t < 8; ++t) o[t] = (short)f32_to_bf16_rne(f[t]);
    *(bf16x8*)(qs + (size_t)id * 8) = o;
}

// ---------------------------------------------------------------------------
// persistent prescreen GEMM + column max
// ---------------------------------------------------------------------------
__launch_bounds__(512, 2)
__global__ void scores_gemm(const float* __restrict__ keys,
                            const unsigned short* __restrict__ qs,
                            float* __restrict__ scores) {
    extern __shared__ char smem[];
    const int tid = threadIdx.x;
    const int w   = tid >> 6;
    const int l   = tid & 63;
    const int g   = l >> 4;
    const int r16 = l & 15;
    const int r7  = r16 & 7;
    const int b   = blockIdx.x;          // 0..255, 1 block/CU

    const int ntile = (NTILES - b + 255) >> 8;   // 4 or 5 tiles
    const int nhalf = ntile * 2;

    char* const al = smem;                       // A tile
    char* const bl = smem + 98304;               // B dbuf
    float* const wmax = (float*)(bl + 32768);    // overlays B buf1 (free at epilogue)

    const char* const qsl = (const char*)qs + (size_t)(w * 64 + l) * 16;
    const int bwr = (w * 64 + l) * 16;           // B ds_write lane offset (+g*8192)

    int abase[3];
#pragma unroll
    for (int rt = 0; rt < 3; ++rt) abase[rt] = (rt * 16 + r16) * 2048;
    int bqoff[4];
#pragma unroll
    for (int ct = 0; ct < 4; ++ct) bqoff[ct] = ((w * 4 + ct) * 16 + r16) * 16;

    f32x4 acc[3][4];
#pragma unroll
    for (int rt = 0; rt < 3; ++rt)
#pragma unroll
        for (int ct = 0; ct < 4; ++ct)
#pragma unroll
            for (int j = 0; j < 4; ++j) acc[rt][ct][j] = 0.f;

    f32x4 Qf[24];        // next-half A staging (f32)
    f32x4 RbA[4], RbB[4];// B reg staging (2 sub-steps ahead)

#define ROWBASE(H) ((b + ((H) >> 1) * 256) * 96 + ((H) & 1) * 48)

#define LOAD_AH(BASE) do {                                                     \
    const int base_ = (BASE);                                                  \
    _Pragma("unroll")                                                          \
    for (int i = 0; i < 24; ++i) {                                             \
        int gc = i * 512 + tid;                                                \
        int grow = base_ + (gc >> 8);                                          \
        if (grow > MK - 1) grow = MK - 1;                                      \
        Qf[i] = *(const f32x4*)(keys + (size_t)grow * 1024 + (gc & 255) * 4);  \
    }                                                                          \
} while (0)

#define WRITE_AH() do {                                                        \
    _Pragma("unroll")                                                          \
    for (int i = 0; i < 24; ++i) {                                             \
        int gc = i * 512 + tid;                                                \
        int row = gc >> 8;                                                     \
        int c16 = (gc & 255) >> 1;                                             \
        unsigned long long pk =                                                \
            (unsigned long long)f32_to_bf16_rne(Qf[i].x)                       \
          | ((unsigned long long)f32_to_bf16_rne(Qf[i].y) << 16)               \
          | ((unsigned long long)f32_to_bf16_rne(Qf[i].z) << 32)               \
          | ((unsigned long long)f32_to_bf16_rne(Qf[i].w) << 48);              \
        *(unsigned long long*)(al + row * 2048 +                               \
            ((c16 ^ (row & 7)) << 4) + (gc & 1) * 8) = pk;                     \
    }                                                                          \
} while (0)

#define LOAD_B(R, KS2) do {                                                    \
    _Pragma("unroll")                                                          \
    for (int g2 = 0; g2 < 4; ++g2)                                             \
        R[g2] = *(const f32x4*)(qsl + (size_t)(((KS2) * 4 + g2) * 512) * 16);  \
} while (0)

#define WRITE_B(R, NXT) do {                                                   \
    _Pragma("unroll")                                                          \
    for (int g2 = 0; g2 < 4; ++g2)                                             \
        *(f32x4*)(bl + (NXT) * 32768 + g2 * 8192 + bwr) = R[g2];               \
} while (0)

#define MFMA_STEP(KS, CUR) do {                                                \
    const int chunk_ = ((((KS) * 4) + g) ^ r7) << 4;                           \
    bf16x8 af[3], bfr[4];                                                      \
    _Pragma("unroll")                                                          \
    for (int rt = 0; rt < 3; ++rt)                                             \
        af[rt] = *(const bf16x8*)(al + abase[rt] + chunk_);                    \
    _Pragma("unroll")                                                          \
    for (int ct = 0; ct < 4; ++ct)                                             \
        bfr[ct] = *(const bf16x8*)(bl + (CUR) * 32768 + g * 8192 + bqoff[ct]); \
    __builtin_amdgcn_s_setprio(1);                                             \
    _Pragma("unroll")                                                          \
    for (int rt = 0; rt < 3; ++rt)                                             \
        _Pragma("unroll")                                                      \
        for (int ct = 0; ct < 4; ++ct)                                         \
            acc[rt][ct] = __builtin_amdgcn_mfma_f32_16x16x32_bf16(             \
                af[rt], bfr[ct], acc[rt][ct], 0, 0, 0);                        \
    __builtin_amdgcn_s_setprio(0);                                             \
} while (0)

#define BAR() do {                                                             \
    asm volatile("s_waitcnt lgkmcnt(0)" ::: "memory");                         \
    __builtin_amdgcn_s_barrier();                                              \
    __builtin_amdgcn_sched_barrier(0);                                         \
} while (0)

    // ---- prologue: A(half0) + B(0) staged, B(1) in regs
    LOAD_AH(ROWBASE(0));
    LOAD_B(RbA, 0);
    LOAD_B(RbB, 1);
    WRITE_AH();             // auto vmcnt wait on A loads
    WRITE_B(RbA, 0);
    __syncthreads();

    for (int half = 0; half < nhalf; ++half) {
        const bool lastH = (half == nhalf - 1);
        if (!lastH) LOAD_AH(ROWBASE(half + 1));   // issue-early: paces this half

        for (int p = 0; p < 16; ++p) {
            const int s0 = 2 * p, s1 = 2 * p + 1;
            // even sub-step: buf0, write B(s0+1) from RbB, load B(s0+2)->RbA
            if (!(lastH && s0 >= 30)) LOAD_B(RbA, (s0 + 2) & 31);
            MFMA_STEP(s0, 0);
            __builtin_amdgcn_sched_barrier(0);
            WRITE_B(RbB, 1);
            BAR();
            // odd sub-step: buf1, write B(s1+1) from RbA, load B(s1+2)->RbB
            if (!(lastH && s1 >= 30)) LOAD_B(RbB, (s1 + 2) & 31);
            MFMA_STEP(s1, 1);
            __builtin_amdgcn_sched_barrier(0);
            if (!(lastH && s1 == 31)) WRITE_B(RbA, 0);
            BAR();
        }

        // ---- half epilogue: stage next A, extract this half's 48 scores
        if (!lastH) WRITE_AH();
#pragma unroll
        for (int rt = 0; rt < 3; ++rt) {
#pragma unroll
            for (int j = 0; j < 4; ++j) {
                float mx = acc[rt][0][j];
                mx = fmaxf(mx, acc[rt][1][j]);
                mx = fmaxf(mx, acc[rt][2][j]);
                mx = fmaxf(mx, acc[rt][3][j]);
#pragma unroll
                for (int off = 1; off < 16; off <<= 1)
                    mx = fmaxf(mx, __shfl_xor(mx, off));
                if (r16 == 0) wmax[w * 48 + rt * 16 + g * 4 + j] = mx;
            }
        }
        BAR();
        {
            const int m0h = ROWBASE(half);
            if (tid < 48) {
                float mx = wmax[tid];
#pragma unroll
                for (int ww = 1; ww < 8; ++ww) mx = fmaxf(mx, wmax[ww * 48 + tid]);
                int gm = m0h + tid;
                if (gm < MK) scores[gm] = mx;
            }
        }
        BAR();   // protect wmax region (B buf1) before next half's ds_writes
#pragma unroll
        for (int rt = 0; rt < 3; ++rt)
#pragma unroll
            for (int ct = 0; ct < 4; ++ct)
#pragma unroll
                for (int j = 0; j < 4; ++j) acc[rt][ct][j] = 0.f;
    }

#undef ROWBASE
#undef LOAD_AH
#undef WRITE_AH
#undef LOAD_B
#undef WRITE_B
#undef MFMA_STEP
#undef BAR
}

// ---------------------------------------------------------------------------
// threshold select, multi-block (unchanged from R8)
// ---------------------------------------------------------------------------
__global__ void zero_hist(unsigned int* __restrict__ hist, int* __restrict__ cnt) {
    int i = blockIdx.x * 1024 + threadIdx.x;
    if (i < 8192) hist[i] = 0;
    if (i == 0) cnt[0] = 0;
}

__global__ void hist_build(const float* __restrict__ scores, unsigned int* __restrict__ hist) {
    __shared__ unsigned int lh[8192];
    for (int i = threadIdx.x; i < 8192; i += 256) lh[i] = 0;
    __syncthreads();
    for (int i = blockIdx.x * 256 + threadIdx.x; i < MK; i += gridDim.x * 256)
        atomicAdd(&lh[xform(scores[i]) >> 19], 1u);
    __syncthreads();
    for (int i = threadIdx.x; i < 8192; i += 256) {
        unsigned int c = lh[i];
        if (c) atomicAdd(&hist[i], c);
    }
}

__launch_bounds__(1024)
__global__ void find_thresh(const unsigned int* __restrict__ hist, float* __restrict__ vlo) {
    __shared__ unsigned int s0[1024], s1[1024];
    const int tid = threadIdx.x;
    unsigned int s = 0;
#pragma unroll
    for (int j = 0; j < 8; ++j) s += hist[tid * 8 + j];
    s0[tid] = s;
    __syncthreads();
    unsigned int* src = s0;
    unsigned int* dst = s1;
    for (int off = 1; off < 1024; off <<= 1) {
        unsigned int v = src[tid] + ((tid + off < 1024) ? src[tid + off] : 0u);
        __syncthreads();
        dst[tid] = v;
        __syncthreads();
        unsigned int* t = src; src = dst; dst = t;
    }
    unsigned int suf  = src[tid];
    unsigned int sufn = (tid < 1023) ? src[tid + 1] : 0u;
    if (suf >= 64u && sufn < 64u) {
        unsigned int acc = sufn;
        int b = tid * 8 + 7;
        for (;; --b) { acc += hist[b]; if (acc >= 64u) break; }
        vlo[0] = unxform(((unsigned int)b) << 19) - 1.0f;   // margin 1.0
    }
}

__global__ void collect(const float* __restrict__ scores, const float* __restrict__ vlo,
                        int* __restrict__ cidx, int* __restrict__ cnt) {
    const float t = vlo[0];
    for (int i = blockIdx.x * 256 + threadIdx.x; i < MK; i += gridDim.x * 256) {
        if (scores[i] >= t) {
            int p = atomicAdd(cnt, 1);
            if (p < CAP) cidx[p] = i;
        }
    }
}

// ---------------------------------------------------------------------------
// exact f32 rescore: one block per candidate, max over 512 queries
// ---------------------------------------------------------------------------
__launch_bounds__(256)
__global__ void rescore(const float* __restrict__ q, const float* __restrict__ a,
                        const float* __restrict__ keys,
                        const int* __restrict__ cidx, const int* __restrict__ cnt,
                        float* __restrict__ resc) {
    __shared__ float wsm[1024];
    __shared__ float smax[4];
    const int b = blockIdx.x;
    if (b >= cnt[0]) return;
    const int m   = cidx[b];
    const int tid = threadIdx.x;

    for (int d = tid; d < 1024; d += 256) wsm[d] = a[d] * keys[(size_t)m * DD + d];
    __syncthreads();

    const int wid = tid >> 6, lane = tid & 63;
    float best = -__builtin_inff();
    for (int n = wid; n < NQ; n += 4) {
        const float* qr = q + (size_t)n * DD;
        float p = 0.f;
#pragma unroll
        for (int j = 0; j < 4; ++j) {
            float4 v  = *(const float4*)(qr + lane * 4 + 256 * j);
            float4 ww = *(const float4*)(&wsm[lane * 4 + 256 * j]);
            p += v.x * ww.x + v.y * ww.y + v.z * ww.z + v.w * ww.w;
        }
#pragma unroll
        for (int off = 1; off < 64; off <<= 1) p += __shfl_xor(p, off);
        best = fmaxf(best, p);
    }
    if (lane == 0) smax[wid] = best;
    __syncthreads();
    if (tid == 0)
        resc[b] = fmaxf(fmaxf(smax[0], smax[1]), fmaxf(smax[2], smax[3]));
}

// ---------------------------------------------------------------------------
// final: top-64 over candidates (exact vals, tie: idx asc), softmax, gather V
// ---------------------------------------------------------------------------
__launch_bounds__(256)
__global__ void final_select(const int* __restrict__ cidx, const float* __restrict__ resc,
                             const int* __restrict__ cnt, const float* __restrict__ values,
                             float* __restrict__ out) {
    __shared__ float selw[64];
    __shared__ int   seli[64];
    const int tid = threadIdx.x;
    int nc = cnt[0];
    if (nc > CAP) nc = CAP;

    if (tid < 64) {
        const int lane = tid;
        float lv[16]; int li[16];
#pragma unroll
        for (int j = 0; j < 16; ++j) {
            int slot = lane + 64 * j;
            bool ok = slot < nc;
            lv[j] = ok ? resc[slot] : -__builtin_inff();
            li[j] = ok ? cidx[slot] : 0x7fffffff;
        }
        for (int it = 0; it < 64; ++it) {
            float bv = -__builtin_inff();
            int bg = 0x7fffffff, bj = 0;
#pragma unroll
            for (int j = 0; j < 16; ++j)
                if (lv[j] > bv || (lv[j] == bv && li[j] < bg)) { bv = lv[j]; bg = li[j]; bj = j; }
            int bcode = (lane << 4) | bj;
#pragma unroll
            for (int off = 1; off < 64; off <<= 1) {
                float ov = __shfl_xor(bv, off);
                int   og = __shfl_xor(bg, off);
                int   oc = __shfl_xor(bcode, off);
                if (ov > bv || (ov == bv && og < bg)) { bv = ov; bg = og; bcode = oc; }
            }
            if ((bcode >> 4) == lane) {
                int wj = bcode & 15;
#pragma unroll
                for (int j = 0; j < 16; ++j) if (j == wj) lv[j] = -__builtin_inff();
            }
            if (lane == 0) { selw[it] = bv; seli[it] = bg; }
        }
    }
    __syncthreads();

    if (tid < 64) {
        float x = selw[tid];
        float mx = x;
#pragma unroll
        for (int off = 1; off < 64; off <<= 1) mx = fmaxf(mx, __shfl_xor(mx, off));
        float e = expf(x - mx);
        float s = e;
#pragma unroll
        for (int off = 1; off < 64; off <<= 1) s += __shfl_xor(s, off);
        selw[tid] = e / s;
        out[DD + tid] = (float)seli[tid];
    }
    __syncthreads();

    for (int d = tid; d < DD; d += 256) {
        float accv = 0.f;
        for (int i = 0; i < 64; ++i)
            accv += selw[i] * values[(size_t)seli[i] * DD + d];
        out[d] = accv;
    }
}

// ---------------------------------------------------------------------------
extern "C" void kernel_launch(void* const* d_in, const int* in_sizes, int n_in,
                              void* d_out, int out_size, void* d_ws, size_t ws_size,
                              hipStream_t stream) {
    (void)in_sizes; (void)n_in; (void)out_size; (void)ws_size;
    const float* queries = (const float*)d_in[0];
    const float* keys    = (const float*)d_in[1];
    const float* values  = (const float*)d_in[2];
    const float* affine  = (const float*)d_in[3];
    float* out = (float*)d_out;
    char*  ws  = (char*)d_ws;

    unsigned short* qstage = (unsigned short*)(ws + QSTAGE_OFF);
    float* scores = (float*)(ws + SCORES_OFF);
    int*   cidx   = (int*)(ws + CIDX_OFF);
    float* resc   = (float*)(ws + RESC_OFF);
    int*   cnt    = (int*)(ws + CNT_OFF);
    unsigned int* hist = (unsigned int*)(ws + HIST_OFF);
    float* vlo    = (float*)(ws + VLO_OFF);

    hipFuncSetAttribute((const void*)scores_gemm,
                        hipFuncAttributeMaxDynamicSharedMemorySize, GEMM_LDS);

    prep_q<<<256, 256, 0, stream>>>(queries, affine, qstage);
    scores_gemm<<<256, 512, GEMM_LDS, stream>>>(keys, qstage, scores);
    zero_hist<<<8, 1024, 0, stream>>>(hist, cnt);
    hist_build<<<64, 256, 0, stream>>>(scores, hist);
    find_thresh<<<1, 1024, 0, stream>>>(hist, vlo);
    collect<<<200, 256, 0, stream>>>(scores, vlo, cidx, cnt);
    rescore<<<CAP, 256, 0, stream>>>(queries, affine, keys, cidx, cnt, resc);
    final_select<<<1, 256, 0, stream>>>(cidx, resc, cnt, values, out);
}